// Round 1
// baseline (1592.245 us; speedup 1.0000x reference)
//
#include <hip/hip_runtime.h>
#include <hip/hip_bf16.h>

// LogVAE. R7 (from R6 @1582us):
//  (1) masked A-frag ds_reads — only lanes with real M-rows (c16%4==0) read LDS;
//      other lanes keep register zeros (init once, outside loop). Cuts LDS read
//      traffic 4x (32KB->8KB/CU/step) and bank conflicts ~4x.
//  (2) raw s_barrier + lgkmcnt(0) only (no vmcnt drain) — __syncthreads was
//      serializing the x global prefetch + hs_out stores into every step.
//      sched_barrier(0) fences both sides (guide rule #18).
//  (3) x-part gx(t) in separate accumulator computed one step ahead; x
//      prefetched two steps ahead. Dependent chain per step: ds_read -> 4 MFMA
//      -> epilogue (was 6 MFMA with x at the end).

#define B_ 256
#define S_ 1024
#define NF_ 32
#define E_ 64
#define H_ 128
#define L_ 64
#define C_ 31

#define ACTS_OFF 0
#define TS_OFF   8118528   // 256*1023*31
#define MU_OFF   8380416   // + 256*1023
#define LV_OFF   8396800   // + 256*64

#define LOG2E  1.44269504f
#define LOG2E2 2.88539008f

typedef __attribute__((ext_vector_type(8))) short short8;
typedef __attribute__((ext_vector_type(4))) float float4v;

__device__ inline unsigned short f2bf(float x){
  union { float f; unsigned u; } a; a.f = x;
  unsigned r = a.u + 0x7FFFu + ((a.u >> 16) & 1u);
  return (unsigned short)(r >> 16);
}
__device__ inline float frcp(float x){
#if __has_builtin(__builtin_amdgcn_rcpf)
  return __builtin_amdgcn_rcpf(x);
#else
  return 1.0f / x;
#endif
}
__device__ inline float fexp2(float x){
#if __has_builtin(__builtin_amdgcn_exp2f)
  return __builtin_amdgcn_exp2f(x);
#else
  return exp2f(x);
#endif
}
__device__ inline float fsig(float x){ return frcp(1.0f + fexp2(-LOG2E*x)); }
__device__ inline float leaky(float x){ return x >= 0.0f ? x : 0.01f*x; }
__device__ inline float wredsum(float v){
  v += __shfl_xor(v, 32, 64);
  v += __shfl_xor(v, 16, 64);
  v += __shfl_xor(v,  8, 64);
  v += __shfl_xor(v,  4, 64);
  v += __shfl_xor(v,  2, 64);
  v += __shfl_xor(v,  1, 64);
  return v;
}

// ---------------- Kernel A: x_emb = LN(leaky(x @ W.T + b)) -> bf16 [S][B][E] --
__global__ __launch_bounds__(256) void init_kernel(
    const float* __restrict__ x, const float* __restrict__ W,
    const float* __restrict__ bias, const float* __restrict__ gam,
    const float* __restrict__ beta, unsigned short* __restrict__ xemb)
{
  // zero the 64-short pad after xemb (stride-0 x-load target for non-batch lanes)
  if (blockIdx.x == 0 && threadIdx.x < 64)
    xemb[(size_t)S_*B_*E_ + threadIdx.x] = 0;

  const int wave = threadIdx.x >> 6, lane = threadIdx.x & 63;
  const int r = blockIdx.x * 4 + wave;        // r = b*S + s (matches x layout)
  const int b = r >> 10, s = r & 1023;
  const float* xr = x + (size_t)r * NF_;
  float xv = (lane < NF_) ? xr[lane] : 0.0f;
  float acc = bias[lane];
  const float* wr = W + lane * NF_;
  #pragma unroll
  for (int k = 0; k < NF_; ++k)
    acc += __shfl(xv, k, 64) * wr[k];
  acc = leaky(acc);
  float m = wredsum(acc) * (1.0f/64.0f);
  float d = acc - m;
  float v = wredsum(d*d) * (1.0f/64.0f);
  float y = d * rsqrtf(v + 1e-5f) * gam[lane] + beta[lane];
  xemb[((size_t)s * B_ + b) * E_ + lane] = f2bf(y);   // [S][B][E]
}

// ---------------- Kernel B: LSTM recurrence ---------------------------------
// grid=64 (4 batch/WG), block=512 (8 waves). Wave w owns i,f,g,o gates of
// hidden [16w,16w+16). Batch b_local -> MFMA row 4*b_local; lane (q,c16)
// epilogues exactly reg r=0 (cell = batch q, hidden unit 16w+c16).
__global__ __launch_bounds__(512, 2) void lstm_kernel(
    const float* __restrict__ Wih,   // [512][64]
    const float* __restrict__ Whh,   // [512][128]
    const float* __restrict__ bih, const float* __restrict__ bhh,
    const unsigned short* __restrict__ xemb,  // [S][256][64] bf16 (+64 zero pad)
    int T,
    const float* __restrict__ h0, const float* __restrict__ c0, // null => ones/zeros
    float* __restrict__ hT_out,               // [256][128] fp32 or null
    unsigned short* __restrict__ hs_out)      // [T][256][128] bf16 or null
{
  __shared__ unsigned short hbuf[2][16*136];  // +8 pad/row
  const int tid = threadIdx.x;
  const int wave = tid >> 6, lane = tid & 63;
  const int q = lane >> 4, c16 = lane & 15;
  const int bt0 = blockIdx.x * 4;
  const int hu = wave * 16 + c16;

  // Persistent B frags: kb 0..3 = Whh (K=0..128), kb 4..5 = Wih (K=128..192)
  short8 Bf[4][6];
  float bias[4];
  #pragma unroll
  for (int g = 0; g < 4; ++g){
    const int gcol = g*128 + hu;
    bias[g] = bih[gcol] + bhh[gcol];
    #pragma unroll
    for (int kb = 0; kb < 6; ++kb){
      union { short8 v; unsigned short u[8]; } tmp;
      #pragma unroll
      for (int j = 0; j < 8; ++j){
        int k = kb*32 + q*8 + j;
        float wv = (kb < 4) ? Whh[gcol*H_ + k] : Wih[gcol*E_ + (k - H_)];
        tmp.u[j] = f2bf(wv);
      }
      Bf[g][kb] = tmp.v;
    }
  }

  // LDS: zero both buffers, then fill rows {0,4,8,12} of buf0 with h0.
  unsigned short* hflat = &hbuf[0][0];
  for (int idx = tid; idx < 2*16*136; idx += 512) hflat[idx] = 0;
  __syncthreads();
  {
    int b = tid >> 7, k = tid & 127;   // tid < 512 = 4*128
    hbuf[0][(4*b)*136 + k] = h0 ? f2bf(h0[((size_t)(bt0 + b))*H_ + k])
                                : (unsigned short)0x3F80; // bf16(1.0)
  }
  float cst = c0 ? c0[((size_t)(bt0 + q))*H_ + hu] : 0.0f;
  __syncthreads();

  // x prefetch: lanes c16%4==0 carry batch c16>>2; others read the zero pad
  // with stride 0. Same predicate selects the real A-rows (M-row = c16).
  const bool is_x = ((c16 & 3) == 0);
  const unsigned short* xp = is_x
      ? (xemb + ((size_t)(bt0 + (c16 >> 2)))*E_ + q*8)
      : (xemb + (size_t)S_*B_*E_ + q*8);
  const size_t xstep = is_x ? (size_t)B_*E_ : 0;

  // gx(0) into xacc; xf holds x(1); loads inside the loop fetch x(t+2).
  short8 a0 = *(const short8*)xp;
  short8 a1 = *(const short8*)(xp + 32);
  xp += xstep;                                   // -> t=1
  float4v xacc[4];
  #pragma unroll
  for (int g = 0; g < 4; ++g){
    float4v xa = (float4v){bias[g], 0.0f, 0.0f, 0.0f};
    xa = __builtin_amdgcn_mfma_f32_16x16x32_bf16(a0, Bf[g][4], xa, 0, 0, 0);
    xacc[g] = __builtin_amdgcn_mfma_f32_16x16x32_bf16(a1, Bf[g][5], xa, 0, 0, 0);
  }
  short8 xf0 = *(const short8*)xp;
  short8 xf1 = *(const short8*)(xp + 32);
  xp += xstep;                                   // -> t=2  (T >= 3 always)

  // A-frag registers: zero once; only real-row lanes ever overwrite them, so
  // the masked ds_read leaves the other 48 lanes' zeros intact (4x less LDS
  // read traffic and conflicts).
  short8 Af[4];
  #pragma unroll
  for (int kb = 0; kb < 4; ++kb) Af[kb] = 0;

  const unsigned short* ha0 = hflat + c16*136 + q*8;          // read base buf0
  const unsigned short* ha1 = ha0 + 2176;                     // read base buf1
  unsigned short* hw0 = hflat + (4*q)*136 + hu;               // write base buf0
  unsigned short* hw1 = hw0 + 2176;                           // write base buf1
  unsigned short* hsp = hs_out ? (hs_out + ((size_t)(bt0 + q))*H_ + hu) : nullptr;

  for (int t = 0; t < T; ++t){
    const unsigned short* ha = (t & 1) ? ha1 : ha0;
    if (is_x){
      #pragma unroll
      for (int kb = 0; kb < 4; ++kb)
        Af[kb] = *(const short8*)(ha + kb*32);
    }

    float4v acc[4];
    #pragma unroll
    for (int g = 0; g < 4; ++g) acc[g] = xacc[g];   // gx(t) precomputed
    #pragma unroll
    for (int kb = 0; kb < 4; ++kb){
      #pragma unroll
      for (int g = 0; g < 4; ++g)
        acc[g] = __builtin_amdgcn_mfma_f32_16x16x32_bf16(Af[kb], Bf[g][kb], acc[g], 0, 0, 0);
    }

    // gx(t+1) off the critical path (xf = x(t+1)); harmless garbage at t=T-1.
    #pragma unroll
    for (int g = 0; g < 4; ++g){
      float4v xa = (float4v){bias[g], 0.0f, 0.0f, 0.0f};
      xa = __builtin_amdgcn_mfma_f32_16x16x32_bf16(xf0, Bf[g][4], xa, 0, 0, 0);
      xacc[g] = __builtin_amdgcn_mfma_f32_16x16x32_bf16(xf1, Bf[g][5], xa, 0, 0, 0);
    }

    // prefetch x(t+2), clamped at the last valid step
    short8 nx0 = *(const short8*)xp;
    short8 nx1 = *(const short8*)(xp + 32);
    if (t + 3 < T) xp += xstep;

    // epilogue: 1 cell/lane (reg r=0). Shared-rcp pairs:
    // sig(i)*tanh(g) = e^i(e^2g-1) / [(1+e^i)(1+e^2g)], same for o/c.
    float gi = acc[0][0], gf = acc[1][0], gg = acc[2][0], go = acc[3][0];
    float ei  = fexp2(gi * LOG2E);
    float e2g = fexp2(gg * LOG2E2);
    float t1  = (ei * (e2g - 1.0f)) * frcp((1.0f + ei) * (1.0f + e2g));
    float sf  = fsig(gf);
    float c   = fmaf(sf, cst, t1);
    cst = c;
    float eo  = fexp2(go * LOG2E);
    float e2c = fexp2(fminf(c * LOG2E2, 126.0f));   // clamp: c can accumulate
    float h   = (eo * (e2c - 1.0f)) * frcp((1.0f + eo) * (1.0f + e2c));

    unsigned short* hw = (t & 1) ? hw0 : hw1;       // write buf (1-cur)
    unsigned short hb16 = f2bf(h);
    hw[0] = hb16;
    if (hs_out){ *hsp = hb16; hsp += (size_t)B_*H_; }
    if (hT_out && t == T-1) hT_out[((size_t)(bt0 + q))*H_ + hu] = h;
    xf0 = nx0; xf1 = nx1;

    // Raw barrier: drain LDS only (ds_write above / ds_read beyond), leave
    // global loads/stores in flight. sched_barrier pins ordering (rule #18).
    __builtin_amdgcn_sched_barrier(0);
    asm volatile("s_waitcnt lgkmcnt(0)" ::: "memory");
    __builtin_amdgcn_s_barrier();
    __builtin_amdgcn_sched_barrier(0);
  }
}

// ---------------- Kernel C: mu/logvar/latent/dh0/dc0 ------------------------
__global__ __launch_bounds__(128) void latent_kernel(
    const float* __restrict__ hT, const float* __restrict__ eps,
    const float* __restrict__ mu_W, const float* __restrict__ mu_b,
    const float* __restrict__ mu_g, const float* __restrict__ mu_be,
    const float* __restrict__ lv_W, const float* __restrict__ lv_b,
    const float* __restrict__ lv_g, const float* __restrict__ lv_be,
    const float* __restrict__ lh_W, const float* __restrict__ lh_b,
    const float* __restrict__ lh_g, const float* __restrict__ lh_be,
    const float* __restrict__ lc_W, const float* __restrict__ lc_b,
    const float* __restrict__ lc_g, const float* __restrict__ lc_be,
    float* __restrict__ out, float* __restrict__ dh0, float* __restrict__ dc0)
{
  const int b = blockIdx.x, tid = threadIdx.x;
  const int wave = tid >> 6, lane = tid & 63;
  __shared__ float shT[H_];
  __shared__ float smu[L_], slv[L_], slat[L_];
  __shared__ float part[2];
  shT[tid] = hT[(size_t)b*H_ + tid];
  __syncthreads();
  {
    const float* W = wave ? lv_W : mu_W;
    float a = (wave ? lv_b : mu_b)[lane];
    for (int k = 0; k < H_; ++k) a += shT[k] * W[lane*H_ + k];
    a = leaky(a);
    float m = wredsum(a) * (1.0f/L_);
    float d = a - m;
    float v = wredsum(d*d) * (1.0f/L_);
    float y = d * rsqrtf(v + 1e-5f) * (wave ? lv_g : mu_g)[lane] + (wave ? lv_be : mu_be)[lane];
    out[(wave ? LV_OFF : MU_OFF) + (size_t)b*L_ + lane] = y;
    if (wave) slv[lane] = y; else smu[lane] = y;
  }
  __syncthreads();
  if (tid < L_) slat[tid] = smu[tid] + eps[(size_t)b*L_ + tid] * expf(0.5f*slv[tid]);
  __syncthreads();
  #pragma unroll 1
  for (int which = 0; which < 2; ++which){
    const float* W = which ? lc_W : lh_W;
    float p = (which ? lc_b : lh_b)[tid];
    for (int k = 0; k < L_; ++k) p += slat[k] * W[tid*L_ + k];
    p = leaky(p);
    float s = wredsum(p);
    if (lane == 0) part[wave] = s;
    __syncthreads();
    float mean = (part[0] + part[1]) * (1.0f/H_);
    __syncthreads();
    float d = p - mean;
    float s2 = wredsum(d*d);
    if (lane == 0) part[wave] = s2;
    __syncthreads();
    float var = (part[0] + part[1]) * (1.0f/H_);
    __syncthreads();
    float y = d * rsqrtf(var + 1e-5f) * (which ? lc_g : lh_g)[tid] + (which ? lc_be : lh_be)[tid];
    (which ? dc0 : dh0)[(size_t)b*H_ + tid] = y;
  }
}

// ---------------- Kernel D: acts/ts heads via MFMA (N=32: 31 acts + ts) -----
__global__ __launch_bounds__(256) void out_kernel(
    const unsigned short* __restrict__ hs,   // [1023][256][128] bf16
    const float* __restrict__ actW, const float* __restrict__ actB,
    const float* __restrict__ timeW, const float* __restrict__ timeB,
    float* __restrict__ out)
{
  const int wave = threadIdx.x >> 6, lane = threadIdx.x & 63;
  const int quad = lane >> 4, c16 = lane & 15;
  const int mt = blockIdx.x * 4 + wave;      // M-tile of 16 rows (r = t*256 + b)
  short8 Wf[2][4]; float biasn[2];
  #pragma unroll
  for (int ti = 0; ti < 2; ++ti){
    const int n = ti*16 + c16;
    biasn[ti] = (n < C_) ? actB[n] : timeB[0];
    #pragma unroll
    for (int kb = 0; kb < 4; ++kb){
      union { short8 v; unsigned short u[8]; } tmp;
      #pragma unroll
      for (int j = 0; j < 8; ++j){
        int k = kb*32 + quad*8 + j;
        tmp.u[j] = f2bf((n < C_) ? actW[n*H_ + k] : timeW[k]);
      }
      Wf[ti][kb] = tmp.v;
    }
  }
  const unsigned short* hp = hs + ((size_t)mt*16 + c16)*H_ + quad*8;
  float4v acc[2];
  #pragma unroll
  for (int ti = 0; ti < 2; ++ti) acc[ti] = (float4v){biasn[ti], biasn[ti], biasn[ti], biasn[ti]};
  #pragma unroll
  for (int kb = 0; kb < 4; ++kb){
    short8 a = *(const short8*)(hp + kb*32);
    acc[0] = __builtin_amdgcn_mfma_f32_16x16x32_bf16(a, Wf[0][kb], acc[0], 0, 0, 0);
    acc[1] = __builtin_amdgcn_mfma_f32_16x16x32_bf16(a, Wf[1][kb], acc[1], 0, 0, 0);
  }
  #pragma unroll
  for (int ti = 0; ti < 2; ++ti){
    const int n = ti*16 + c16;
    #pragma unroll
    for (int r = 0; r < 4; ++r){
      int rr = mt*16 + quad*4 + r;
      int tt = rr >> 8, b = rr & 255;
      float v = acc[ti][r];
      if (n < C_) out[ACTS_OFF + ((size_t)b*1023 + tt)*C_ + n] = v;
      else        out[TS_OFF + (size_t)b*1023 + tt] = v;
    }
  }
}

// ---------------- launch ----------------------------------------------------
extern "C" void kernel_launch(void* const* d_in, const int* in_sizes, int n_in,
                              void* d_out, int out_size, void* d_ws, size_t ws_size,
                              hipStream_t stream)
{
  (void)in_sizes; (void)n_in; (void)out_size; (void)ws_size;
  const float* x       = (const float*)d_in[0];
  const float* eps     = (const float*)d_in[1];
  const float* init_W  = (const float*)d_in[2];
  const float* init_b  = (const float*)d_in[3];
  const float* init_g  = (const float*)d_in[4];
  const float* init_be = (const float*)d_in[5];
  const float* enc_Wih = (const float*)d_in[6];
  const float* enc_Whh = (const float*)d_in[7];
  const float* enc_bih = (const float*)d_in[8];
  const float* enc_bhh = (const float*)d_in[9];
  const float* mu_W  = (const float*)d_in[10];
  const float* mu_b  = (const float*)d_in[11];
  const float* mu_g  = (const float*)d_in[12];
  const float* mu_be = (const float*)d_in[13];
  const float* lv_W  = (const float*)d_in[14];
  const float* lv_b  = (const float*)d_in[15];
  const float* lv_g  = (const float*)d_in[16];
  const float* lv_be = (const float*)d_in[17];
  const float* dec_Wih = (const float*)d_in[18];
  const float* dec_Whh = (const float*)d_in[19];
  const float* dec_bih = (const float*)d_in[20];
  const float* dec_bhh = (const float*)d_in[21];
  const float* lh_W  = (const float*)d_in[22];
  const float* lh_b  = (const float*)d_in[23];
  const float* lh_g  = (const float*)d_in[24];
  const float* lh_be = (const float*)d_in[25];
  const float* lc_W  = (const float*)d_in[26];
  const float* lc_b  = (const float*)d_in[27];
  const float* lc_g  = (const float*)d_in[28];
  const float* lc_be = (const float*)d_in[29];
  const float* act_W  = (const float*)d_in[30];
  const float* act_b  = (const float*)d_in[31];
  const float* time_W = (const float*)d_in[32];
  const float* time_b = (const float*)d_in[33];
  float* out = (float*)d_out;

  // workspace: xemb [1024][256][64] bf16 + 64-short zero pad, hs, hT, dh0, dc0
  unsigned short* xemb = (unsigned short*)d_ws;
  unsigned short* hs   = xemb + (size_t)S_*B_*E_ + 64;       // after pad
  float* hT  = (float*)(hs + (size_t)(S_-1)*B_*H_);
  float* dh0 = hT  + B_*H_;
  float* dc0 = dh0 + B_*H_;

  init_kernel<<<dim3((B_*S_)/4), dim3(256), 0, stream>>>(
      x, init_W, init_b, init_g, init_be, xemb);

  lstm_kernel<<<dim3(64), dim3(512), 0, stream>>>(
      enc_Wih, enc_Whh, enc_bih, enc_bhh, xemb, S_,
      nullptr, nullptr, hT, nullptr);

  latent_kernel<<<dim3(B_), dim3(128), 0, stream>>>(
      hT, eps, mu_W, mu_b, mu_g, mu_be, lv_W, lv_b, lv_g, lv_be,
      lh_W, lh_b, lh_g, lh_be, lc_W, lc_b, lc_g, lc_be, out, dh0, dc0);

  lstm_kernel<<<dim3(64), dim3(512), 0, stream>>>(
      dec_Wih, dec_Whh, dec_bih, dec_bhh, xemb, S_-1,
      dh0, dc0, nullptr, hs);

  out_kernel<<<dim3((B_*(S_-1))/16/4), dim3(256), 0, stream>>>(
      hs, act_W, act_b, time_W, time_b, out);
}

// Round 2
// 1416.957 us; speedup vs baseline: 1.1237x; 1.1237x over previous
//
#include <hip/hip_runtime.h>
#include <hip/hip_bf16.h>

// LogVAE. R8 (from R7 @1592us, conflicts=0 but no speedup):
//  Post-mortem R7: LDS was never the bottleneck. Theory: per-step exposed
//  vmcnt stall on the x prefetch (xf0=nx0 copy forces the wait inside each
//  iteration, pinned by sched_barrier) + 8 wasted x-MFMAs/step.
//  (1) TIME-BATCHED gx: A-rows = (batch,dt) -> one 8-MFMA cluster computes
//      gx for 4 steps (all 16 M rows real). In-loop x-MFMA 8->2 per step.
//  (2) 4-step window pipeline, zero copies: gxB computed at dt=0 from nx
//      (loaded 3 steps earlier), nx reloaded at dt=1 for window w+2.
//      One vmcnt wait per 4 steps with ~3 steps of slack.
//  (3) f2bf (4 dependent ALU) -> v_cvt_pk_bf16_f32 (1 instr) on the
//      h -> ds_write critical chain.

#define B_ 256
#define S_ 1024
#define NF_ 32
#define E_ 64
#define H_ 128
#define L_ 64
#define C_ 31

#define ACTS_OFF 0
#define TS_OFF   8118528   // 256*1023*31
#define MU_OFF   8380416   // + 256*1023
#define LV_OFF   8396800   // + 256*64

#define LOG2E  1.44269504f
#define LOG2E2 2.88539008f

typedef __attribute__((ext_vector_type(8))) short short8;
typedef __attribute__((ext_vector_type(4))) float float4v;

__device__ inline unsigned short f2bf(float x){
  union { float f; unsigned u; } a; a.f = x;
  unsigned r = a.u + 0x7FFFu + ((a.u >> 16) & 1u);
  return (unsigned short)(r >> 16);
}
__device__ inline float frcp(float x){
#if __has_builtin(__builtin_amdgcn_rcpf)
  return __builtin_amdgcn_rcpf(x);
#else
  return 1.0f / x;
#endif
}
__device__ inline float fexp2(float x){
#if __has_builtin(__builtin_amdgcn_exp2f)
  return __builtin_amdgcn_exp2f(x);
#else
  return exp2f(x);
#endif
}
__device__ inline float fsig(float x){ return frcp(1.0f + fexp2(-LOG2E*x)); }
__device__ inline float leaky(float x){ return x >= 0.0f ? x : 0.01f*x; }
__device__ inline float wredsum(float v){
  v += __shfl_xor(v, 32, 64);
  v += __shfl_xor(v, 16, 64);
  v += __shfl_xor(v,  8, 64);
  v += __shfl_xor(v,  4, 64);
  v += __shfl_xor(v,  2, 64);
  v += __shfl_xor(v,  1, 64);
  return v;
}

// ---------------- Kernel A: x_emb = LN(leaky(x @ W.T + b)) -> bf16 [S][B][E] --
__global__ __launch_bounds__(256) void init_kernel(
    const float* __restrict__ x, const float* __restrict__ W,
    const float* __restrict__ bias, const float* __restrict__ gam,
    const float* __restrict__ beta, unsigned short* __restrict__ xemb)
{
  if (blockIdx.x == 0 && threadIdx.x < 64)
    xemb[(size_t)S_*B_*E_ + threadIdx.x] = 0;

  const int wave = threadIdx.x >> 6, lane = threadIdx.x & 63;
  const int r = blockIdx.x * 4 + wave;        // r = b*S + s (matches x layout)
  const int b = r >> 10, s = r & 1023;
  const float* xr = x + (size_t)r * NF_;
  float xv = (lane < NF_) ? xr[lane] : 0.0f;
  float acc = bias[lane];
  const float* wr = W + lane * NF_;
  #pragma unroll
  for (int k = 0; k < NF_; ++k)
    acc += __shfl(xv, k, 64) * wr[k];
  acc = leaky(acc);
  float m = wredsum(acc) * (1.0f/64.0f);
  float d = acc - m;
  float v = wredsum(d*d) * (1.0f/64.0f);
  float y = d * rsqrtf(v + 1e-5f) * gam[lane] + beta[lane];
  xemb[((size_t)s * B_ + b) * E_ + lane] = f2bf(y);   // [S][B][E]
}

// ---------------- Kernel B: LSTM recurrence ---------------------------------
// grid=64 (4 batch/WG), block=512 (8 waves). Wave w owns i,f,g,o gates of
// hidden [16w,16w+16). h-MFMA M rows {0,4,8,12} = batches; lane (q,c16)
// epilogues reg r=0 (cell = batch q, hidden unit 16w+c16).
// gx is time-batched: A rows = 4*b+dt; gx MFMA reg r = gx(t0+r) for batch q.
__global__ __launch_bounds__(512, 2) void lstm_kernel(
    const float* __restrict__ Wih,   // [512][64]
    const float* __restrict__ Whh,   // [512][128]
    const float* __restrict__ bih, const float* __restrict__ bhh,
    const unsigned short* __restrict__ xemb,  // [S][256][64] bf16 (+64 zero pad)
    int T,
    const float* __restrict__ h0, const float* __restrict__ c0, // null => ones/zeros
    float* __restrict__ hT_out,               // [256][128] fp32 or null
    unsigned short* __restrict__ hs_out)      // [T][256][128] bf16 or null
{
  __shared__ unsigned short hbuf[2][16*136];  // +8 pad/row
  const int tid = threadIdx.x;
  const int wave = tid >> 6, lane = tid & 63;
  const int q = lane >> 4, c16 = lane & 15;
  const int bt0 = blockIdx.x * 4;
  const int hu = wave * 16 + c16;

  // Persistent B frags: kb 0..3 = Whh (K=0..128), kb 4..5 = Wih (K=128..192)
  short8 Bf[4][6];
  float bias[4];
  #pragma unroll
  for (int g = 0; g < 4; ++g){
    const int gcol = g*128 + hu;
    bias[g] = bih[gcol] + bhh[gcol];
    #pragma unroll
    for (int kb = 0; kb < 6; ++kb){
      union { short8 v; unsigned short u[8]; } tmp;
      #pragma unroll
      for (int j = 0; j < 8; ++j){
        int k = kb*32 + q*8 + j;
        float wv = (kb < 4) ? Whh[gcol*H_ + k] : Wih[gcol*E_ + (k - H_)];
        tmp.u[j] = f2bf(wv);
      }
      Bf[g][kb] = tmp.v;
    }
  }

  // LDS: zero both buffers, then fill rows {0,4,8,12} of buf0 with h0.
  unsigned short* hflat = &hbuf[0][0];
  for (int idx = tid; idx < 2*16*136; idx += 512) hflat[idx] = 0;
  __syncthreads();
  {
    int b = tid >> 7, k = tid & 127;   // tid < 512 = 4*128
    hbuf[0][(4*b)*136 + k] = h0 ? f2bf(h0[((size_t)(bt0 + b))*H_ + k])
                                : (unsigned short)0x3F80; // bf16(1.0)
  }
  float cst = c0 ? c0[((size_t)(bt0 + q))*H_ + hu] : 0.0f;
  __syncthreads();

  const bool is_x = ((c16 & 3) == 0);   // lanes whose A-row {0,4,8,12} is real

  // x window loads: ALL 64 lanes real. Lane A-row = c16 = 4*b_local + dt.
  const int xb = c16 >> 2, xdt = c16 & 3;
  const unsigned short* xbase = xemb + ((size_t)(bt0 + xb))*E_ + q*8;
  const size_t xrow = (size_t)B_*E_;
  auto xwin = [&](int wt)->const unsigned short*{
    int tt = wt + xdt; if (tt > T-1) tt = T-1;   // clamp: garbage rows unused
    return xbase + (size_t)tt * xrow;
  };

  // Prologue: gxA = gx(0..3); nx = x(4..7) in flight.
  float4v gxA[4], gxB[4];
  short8 nx0, nx1;
  { const unsigned short* p = xwin(0);
    nx0 = *(const short8*)p; nx1 = *(const short8*)(p + 32); }
  #pragma unroll
  for (int g = 0; g < 4; ++g){
    float4v t = (float4v){bias[g], bias[g], bias[g], bias[g]};
    t = __builtin_amdgcn_mfma_f32_16x16x32_bf16(nx0, Bf[g][4], t, 0, 0, 0);
    gxA[g] = __builtin_amdgcn_mfma_f32_16x16x32_bf16(nx1, Bf[g][5], t, 0, 0, 0);
  }
  { const unsigned short* p = xwin(4);
    nx0 = *(const short8*)p; nx1 = *(const short8*)(p + 32); }

  short8 Af0 = 0, Af1 = 0, Af2 = 0, Af3 = 0;   // zeros persist on !is_x lanes

  const unsigned short* ha0 = hflat + c16*136 + q*8;
  const unsigned short* ha1 = ha0 + 2176;
  unsigned short* hw0 = hflat + (4*q)*136 + hu;
  unsigned short* hw1 = hw0 + 2176;
  unsigned short* hsp = hs_out ? (hs_out + ((size_t)(bt0 + q))*H_ + hu) : nullptr;
  float zero_f = 0.0f;

  auto step = [&](int t, float gxi, float gxf, float gxg, float gxo, auto&& extra){
    const unsigned short* ha = (t & 1) ? ha1 : ha0;
    if (is_x){
      Af0 = *(const short8*)(ha);
      Af1 = *(const short8*)(ha + 32);
      Af2 = *(const short8*)(ha + 64);
      Af3 = *(const short8*)(ha + 96);
    }
    float4v a0 = (float4v){gxi, 0.0f, 0.0f, 0.0f};
    float4v a1 = (float4v){gxf, 0.0f, 0.0f, 0.0f};
    float4v a2 = (float4v){gxg, 0.0f, 0.0f, 0.0f};
    float4v a3 = (float4v){gxo, 0.0f, 0.0f, 0.0f};
    a0 = __builtin_amdgcn_mfma_f32_16x16x32_bf16(Af0, Bf[0][0], a0, 0, 0, 0);
    a1 = __builtin_amdgcn_mfma_f32_16x16x32_bf16(Af0, Bf[1][0], a1, 0, 0, 0);
    a2 = __builtin_amdgcn_mfma_f32_16x16x32_bf16(Af0, Bf[2][0], a2, 0, 0, 0);
    a3 = __builtin_amdgcn_mfma_f32_16x16x32_bf16(Af0, Bf[3][0], a3, 0, 0, 0);
    a0 = __builtin_amdgcn_mfma_f32_16x16x32_bf16(Af1, Bf[0][1], a0, 0, 0, 0);
    a1 = __builtin_amdgcn_mfma_f32_16x16x32_bf16(Af1, Bf[1][1], a1, 0, 0, 0);
    a2 = __builtin_amdgcn_mfma_f32_16x16x32_bf16(Af1, Bf[2][1], a2, 0, 0, 0);
    a3 = __builtin_amdgcn_mfma_f32_16x16x32_bf16(Af1, Bf[3][1], a3, 0, 0, 0);
    a0 = __builtin_amdgcn_mfma_f32_16x16x32_bf16(Af2, Bf[0][2], a0, 0, 0, 0);
    a1 = __builtin_amdgcn_mfma_f32_16x16x32_bf16(Af2, Bf[1][2], a1, 0, 0, 0);
    a2 = __builtin_amdgcn_mfma_f32_16x16x32_bf16(Af2, Bf[2][2], a2, 0, 0, 0);
    a3 = __builtin_amdgcn_mfma_f32_16x16x32_bf16(Af2, Bf[3][2], a3, 0, 0, 0);
    a0 = __builtin_amdgcn_mfma_f32_16x16x32_bf16(Af3, Bf[0][3], a0, 0, 0, 0);
    a1 = __builtin_amdgcn_mfma_f32_16x16x32_bf16(Af3, Bf[1][3], a1, 0, 0, 0);
    a2 = __builtin_amdgcn_mfma_f32_16x16x32_bf16(Af3, Bf[2][3], a2, 0, 0, 0);
    a3 = __builtin_amdgcn_mfma_f32_16x16x32_bf16(Af3, Bf[3][3], a3, 0, 0, 0);
    extra();   // window bookkeeping: latency-tolerant slot (accs in flight)
    // epilogue: 1 cell/lane (reg r=0). Shared-rcp pairs:
    // sig(i)*tanh(g) = e^i(e^2g-1) / [(1+e^i)(1+e^2g)], same for o/c.
    float gi = a0[0], gf = a1[0], gg = a2[0], go = a3[0];
    float ei  = fexp2(gi * LOG2E);
    float e2g = fexp2(gg * LOG2E2);
    float t1  = (ei * (e2g - 1.0f)) * frcp((1.0f + ei) * (1.0f + e2g));
    float sf  = fsig(gf);
    float c   = fmaf(sf, cst, t1);
    cst = c;
    float eo  = fexp2(go * LOG2E);
    float e2c = fexp2(fminf(c * LOG2E2, 126.0f));   // clamp: c can accumulate
    float h   = (eo * (e2c - 1.0f)) * frcp((1.0f + eo) * (1.0f + e2c));
    unsigned vv;
    asm("v_cvt_pk_bf16_f32 %0, %1, %2" : "=v"(vv) : "v"(h), "v"(zero_f));
    unsigned short hb16 = (unsigned short)vv;
    unsigned short* hw = (t & 1) ? hw0 : hw1;       // write buf (1-cur)
    hw[0] = hb16;
    if (hs_out){ *hsp = hb16; hsp += (size_t)B_*H_; }
    if (hT_out && t == T-1) hT_out[((size_t)(bt0 + q))*H_ + hu] = h;
    // Raw barrier: drain LDS only; globals stay in flight (R7).
    __builtin_amdgcn_sched_barrier(0);
    asm volatile("s_waitcnt lgkmcnt(0)" ::: "memory");
    __builtin_amdgcn_s_barrier();
    __builtin_amdgcn_sched_barrier(0);
  };

  const int nwin = T >> 2, ntail = T & 3;
  for (int w = 0; w < nwin; ++w){
    const int t0 = w << 2;
    step(t0+0, gxA[0][0], gxA[1][0], gxA[2][0], gxA[3][0], [&]{
      // gxB = gx(t0+4 .. t0+7); consumes nx loaded 3 steps ago.
      #pragma unroll
      for (int g = 0; g < 4; ++g){
        float4v tt = (float4v){bias[g], bias[g], bias[g], bias[g]};
        tt = __builtin_amdgcn_mfma_f32_16x16x32_bf16(nx0, Bf[g][4], tt, 0, 0, 0);
        gxB[g] = __builtin_amdgcn_mfma_f32_16x16x32_bf16(nx1, Bf[g][5], tt, 0, 0, 0);
      }
    });
    step(t0+1, gxA[0][1], gxA[1][1], gxA[2][1], gxA[3][1], [&]{
      // issue loads for window w+2; consumed 3 steps later (dt=0 of w+1).
      const unsigned short* p = xwin(t0 + 8);
      nx0 = *(const short8*)p; nx1 = *(const short8*)(p + 32);
    });
    step(t0+2, gxA[0][2], gxA[1][2], gxA[2][2], gxA[3][2], [&]{});
    step(t0+3, gxA[0][3], gxA[1][3], gxA[2][3], gxA[3][3], [&]{
      #pragma unroll
      for (int g = 0; g < 4; ++g) gxA[g] = gxB[g];   // 16 v_movs / 4 steps
    });
  }
  // Tail (decoder T=1023: 3 steps). gxA already holds gx(nwin*4 ..).
  if (ntail > 0) step(nwin*4+0, gxA[0][0], gxA[1][0], gxA[2][0], gxA[3][0], [&]{});
  if (ntail > 1) step(nwin*4+1, gxA[0][1], gxA[1][1], gxA[2][1], gxA[3][1], [&]{});
  if (ntail > 2) step(nwin*4+2, gxA[0][2], gxA[1][2], gxA[2][2], gxA[3][2], [&]{});
}

// ---------------- Kernel C: mu/logvar/latent/dh0/dc0 ------------------------
__global__ __launch_bounds__(128) void latent_kernel(
    const float* __restrict__ hT, const float* __restrict__ eps,
    const float* __restrict__ mu_W, const float* __restrict__ mu_b,
    const float* __restrict__ mu_g, const float* __restrict__ mu_be,
    const float* __restrict__ lv_W, const float* __restrict__ lv_b,
    const float* __restrict__ lv_g, const float* __restrict__ lv_be,
    const float* __restrict__ lh_W, const float* __restrict__ lh_b,
    const float* __restrict__ lh_g, const float* __restrict__ lh_be,
    const float* __restrict__ lc_W, const float* __restrict__ lc_b,
    const float* __restrict__ lc_g, const float* __restrict__ lc_be,
    float* __restrict__ out, float* __restrict__ dh0, float* __restrict__ dc0)
{
  const int b = blockIdx.x, tid = threadIdx.x;
  const int wave = tid >> 6, lane = tid & 63;
  __shared__ float shT[H_];
  __shared__ float smu[L_], slv[L_], slat[L_];
  __shared__ float part[2];
  shT[tid] = hT[(size_t)b*H_ + tid];
  __syncthreads();
  {
    const float* W = wave ? lv_W : mu_W;
    float a = (wave ? lv_b : mu_b)[lane];
    for (int k = 0; k < H_; ++k) a += shT[k] * W[lane*H_ + k];
    a = leaky(a);
    float m = wredsum(a) * (1.0f/L_);
    float d = a - m;
    float v = wredsum(d*d) * (1.0f/L_);
    float y = d * rsqrtf(v + 1e-5f) * (wave ? lv_g : mu_g)[lane] + (wave ? lv_be : mu_be)[lane];
    out[(wave ? LV_OFF : MU_OFF) + (size_t)b*L_ + lane] = y;
    if (wave) slv[lane] = y; else smu[lane] = y;
  }
  __syncthreads();
  if (tid < L_) slat[tid] = smu[tid] + eps[(size_t)b*L_ + tid] * expf(0.5f*slv[tid]);
  __syncthreads();
  #pragma unroll 1
  for (int which = 0; which < 2; ++which){
    const float* W = which ? lc_W : lh_W;
    float p = (which ? lc_b : lh_b)[tid];
    for (int k = 0; k < L_; ++k) p += slat[k] * W[tid*L_ + k];
    p = leaky(p);
    float s = wredsum(p);
    if (lane == 0) part[wave] = s;
    __syncthreads();
    float mean = (part[0] + part[1]) * (1.0f/H_);
    __syncthreads();
    float d = p - mean;
    float s2 = wredsum(d*d);
    if (lane == 0) part[wave] = s2;
    __syncthreads();
    float var = (part[0] + part[1]) * (1.0f/H_);
    __syncthreads();
    float y = d * rsqrtf(var + 1e-5f) * (which ? lc_g : lh_g)[tid] + (which ? lc_be : lh_be)[tid];
    (which ? dc0 : dh0)[(size_t)b*H_ + tid] = y;
  }
}

// ---------------- Kernel D: acts/ts heads via MFMA (N=32: 31 acts + ts) -----
__global__ __launch_bounds__(256) void out_kernel(
    const unsigned short* __restrict__ hs,   // [1023][256][128] bf16
    const float* __restrict__ actW, const float* __restrict__ actB,
    const float* __restrict__ timeW, const float* __restrict__ timeB,
    float* __restrict__ out)
{
  const int wave = threadIdx.x >> 6, lane = threadIdx.x & 63;
  const int quad = lane >> 4, c16 = lane & 15;
  const int mt = blockIdx.x * 4 + wave;      // M-tile of 16 rows (r = t*256 + b)
  short8 Wf[2][4]; float biasn[2];
  #pragma unroll
  for (int ti = 0; ti < 2; ++ti){
    const int n = ti*16 + c16;
    biasn[ti] = (n < C_) ? actB[n] : timeB[0];
    #pragma unroll
    for (int kb = 0; kb < 4; ++kb){
      union { short8 v; unsigned short u[8]; } tmp;
      #pragma unroll
      for (int j = 0; j < 8; ++j){
        int k = kb*32 + quad*8 + j;
        tmp.u[j] = f2bf((n < C_) ? actW[n*H_ + k] : timeW[k]);
      }
      Wf[ti][kb] = tmp.v;
    }
  }
  const unsigned short* hp = hs + ((size_t)mt*16 + c16)*H_ + quad*8;
  float4v acc[2];
  #pragma unroll
  for (int ti = 0; ti < 2; ++ti) acc[ti] = (float4v){biasn[ti], biasn[ti], biasn[ti], biasn[ti]};
  #pragma unroll
  for (int kb = 0; kb < 4; ++kb){
    short8 a = *(const short8*)(hp + kb*32);
    acc[0] = __builtin_amdgcn_mfma_f32_16x16x32_bf16(a, Wf[0][kb], acc[0], 0, 0, 0);
    acc[1] = __builtin_amdgcn_mfma_f32_16x16x32_bf16(a, Wf[1][kb], acc[1], 0, 0, 0);
  }
  #pragma unroll
  for (int ti = 0; ti < 2; ++ti){
    const int n = ti*16 + c16;
    #pragma unroll
    for (int r = 0; r < 4; ++r){
      int rr = mt*16 + quad*4 + r;
      int tt = rr >> 8, b = rr & 255;
      float v = acc[ti][r];
      if (n < C_) out[ACTS_OFF + ((size_t)b*1023 + tt)*C_ + n] = v;
      else        out[TS_OFF + (size_t)b*1023 + tt] = v;
    }
  }
}

// ---------------- launch ----------------------------------------------------
extern "C" void kernel_launch(void* const* d_in, const int* in_sizes, int n_in,
                              void* d_out, int out_size, void* d_ws, size_t ws_size,
                              hipStream_t stream)
{
  (void)in_sizes; (void)n_in; (void)out_size; (void)ws_size;
  const float* x       = (const float*)d_in[0];
  const float* eps     = (const float*)d_in[1];
  const float* init_W  = (const float*)d_in[2];
  const float* init_b  = (const float*)d_in[3];
  const float* init_g  = (const float*)d_in[4];
  const float* init_be = (const float*)d_in[5];
  const float* enc_Wih = (const float*)d_in[6];
  const float* enc_Whh = (const float*)d_in[7];
  const float* enc_bih = (const float*)d_in[8];
  const float* enc_bhh = (const float*)d_in[9];
  const float* mu_W  = (const float*)d_in[10];
  const float* mu_b  = (const float*)d_in[11];
  const float* mu_g  = (const float*)d_in[12];
  const float* mu_be = (const float*)d_in[13];
  const float* lv_W  = (const float*)d_in[14];
  const float* lv_b  = (const float*)d_in[15];
  const float* lv_g  = (const float*)d_in[16];
  const float* lv_be = (const float*)d_in[17];
  const float* dec_Wih = (const float*)d_in[18];
  const float* dec_Whh = (const float*)d_in[19];
  const float* dec_bih = (const float*)d_in[20];
  const float* dec_bhh = (const float*)d_in[21];
  const float* lh_W  = (const float*)d_in[22];
  const float* lh_b  = (const float*)d_in[23];
  const float* lh_g  = (const float*)d_in[24];
  const float* lh_be = (const float*)d_in[25];
  const float* lc_W  = (const float*)d_in[26];
  const float* lc_b  = (const float*)d_in[27];
  const float* lc_g  = (const float*)d_in[28];
  const float* lc_be = (const float*)d_in[29];
  const float* act_W  = (const float*)d_in[30];
  const float* act_b  = (const float*)d_in[31];
  const float* time_W = (const float*)d_in[32];
  const float* time_b = (const float*)d_in[33];
  float* out = (float*)d_out;

  // workspace: xemb [1024][256][64] bf16 + 64-short zero pad, hs, hT, dh0, dc0
  unsigned short* xemb = (unsigned short*)d_ws;
  unsigned short* hs   = xemb + (size_t)S_*B_*E_ + 64;       // after pad
  float* hT  = (float*)(hs + (size_t)(S_-1)*B_*H_);
  float* dh0 = hT  + B_*H_;
  float* dc0 = dh0 + B_*H_;

  init_kernel<<<dim3((B_*S_)/4), dim3(256), 0, stream>>>(
      x, init_W, init_b, init_g, init_be, xemb);

  lstm_kernel<<<dim3(64), dim3(512), 0, stream>>>(
      enc_Wih, enc_Whh, enc_bih, enc_bhh, xemb, S_,
      nullptr, nullptr, hT, nullptr);

  latent_kernel<<<dim3(B_), dim3(128), 0, stream>>>(
      hT, eps, mu_W, mu_b, mu_g, mu_be, lv_W, lv_b, lv_g, lv_be,
      lh_W, lh_b, lh_g, lh_be, lc_W, lc_b, lc_g, lc_be, out, dh0, dc0);

  lstm_kernel<<<dim3(64), dim3(512), 0, stream>>>(
      dec_Wih, dec_Whh, dec_bih, dec_bhh, xemb, S_-1,
      dh0, dc0, nullptr, hs);

  out_kernel<<<dim3((B_*(S_-1))/16/4), dim3(256), 0, stream>>>(
      hs, act_W, act_b, time_W, time_b, out);
}

// Round 6
// 1353.957 us; speedup vs baseline: 1.1760x; 1.0465x over previous
//
#include <hip/hip_runtime.h>
#include <hip/hip_bf16.h>
#include <type_traits>

// LogVAE. R12 = R11 + lane-rotation fix for the C-in/reg-dt mismatch.
//  R11 FAILED verification (absmax 0.40): h-product lands only at reg 0
//  (real A-rows {0,4,8,12}), but gates were read at reg dt -> recurrent
//  term missing for dt!=0.
//  Fix: at step dt, lanes with (c16&3)==dt supply the h A-rows (address
//  (c16&~3)*136, constant across dt; only the predicate rotates). Real
//  A-rows become {dt,4+dt,8+dt,12+dt} -> h-product lands at reg dt,
//  matching the gx C-in and the [dt] gate read. Stale Af rows on other
//  lanes only affect unread regs.
//  Kept from R9/R11: gx C-in trick (no acc-init movs), K-split 2x2-deep
//  MFMA chains, pre()/post() hooks, time-batched gx (2 x-MFMA/step),
//  4-step x pipeline, lgkmcnt-only barrier, v_cvt_pk_bf16_f32.

#define B_ 256
#define S_ 1024
#define NF_ 32
#define E_ 64
#define H_ 128
#define L_ 64
#define C_ 31

#define ACTS_OFF 0
#define TS_OFF   8118528   // 256*1023*31
#define MU_OFF   8380416   // + 256*1023
#define LV_OFF   8396800   // + 256*64

#define LOG2E  1.44269504f
#define LOG2E2 2.88539008f

typedef __attribute__((ext_vector_type(8))) short short8;
typedef __attribute__((ext_vector_type(4))) float float4v;

__device__ inline unsigned short f2bf(float x){
  union { float f; unsigned u; } a; a.f = x;
  unsigned r = a.u + 0x7FFFu + ((a.u >> 16) & 1u);
  return (unsigned short)(r >> 16);
}
__device__ inline float frcp(float x){
#if __has_builtin(__builtin_amdgcn_rcpf)
  return __builtin_amdgcn_rcpf(x);
#else
  return 1.0f / x;
#endif
}
__device__ inline float fexp2(float x){
#if __has_builtin(__builtin_amdgcn_exp2f)
  return __builtin_amdgcn_exp2f(x);
#else
  return exp2f(x);
#endif
}
__device__ inline float fsig(float x){ return frcp(1.0f + fexp2(-LOG2E*x)); }
__device__ inline float leaky(float x){ return x >= 0.0f ? x : 0.01f*x; }
__device__ inline float wredsum(float v){
  v += __shfl_xor(v, 32, 64);
  v += __shfl_xor(v, 16, 64);
  v += __shfl_xor(v,  8, 64);
  v += __shfl_xor(v,  4, 64);
  v += __shfl_xor(v,  2, 64);
  v += __shfl_xor(v,  1, 64);
  return v;
}

// ---------------- Kernel A: x_emb = LN(leaky(x @ W.T + b)) -> bf16 [S][B][E] --
__global__ __launch_bounds__(256) void init_kernel(
    const float* __restrict__ x, const float* __restrict__ W,
    const float* __restrict__ bias, const float* __restrict__ gam,
    const float* __restrict__ beta, unsigned short* __restrict__ xemb)
{
  if (blockIdx.x == 0 && threadIdx.x < 64)
    xemb[(size_t)S_*B_*E_ + threadIdx.x] = 0;

  const int wave = threadIdx.x >> 6, lane = threadIdx.x & 63;
  const int r = blockIdx.x * 4 + wave;        // r = b*S + s (matches x layout)
  const int b = r >> 10, s = r & 1023;
  const float* xr = x + (size_t)r * NF_;
  float xv = (lane < NF_) ? xr[lane] : 0.0f;
  float acc = bias[lane];
  const float* wr = W + lane * NF_;
  #pragma unroll
  for (int k = 0; k < NF_; ++k)
    acc += __shfl(xv, k, 64) * wr[k];
  acc = leaky(acc);
  float m = wredsum(acc) * (1.0f/64.0f);
  float d = acc - m;
  float v = wredsum(d*d) * (1.0f/64.0f);
  float y = d * rsqrtf(v + 1e-5f) * gam[lane] + beta[lane];
  xemb[((size_t)s * B_ + b) * E_ + lane] = f2bf(y);   // [S][B][E]
}

// ---------------- Kernel B: LSTM recurrence ---------------------------------
// grid=64 (4 batch/WG), block=512 (8 waves). Wave w owns i,f,g,o gates of
// hidden [16w,16w+16). At step dt (t mod 4), h A-rows = {dt,4+dt,8+dt,12+dt}
// (batch b at row 4b+dt, supplied by lanes c16&3==dt) -> h-product lands at
// reg dt = same slot as time-batched gx (A rows 4b+dt) and the gate read.
__global__ __launch_bounds__(512, 2) void lstm_kernel(
    const float* __restrict__ Wih,   // [512][64]
    const float* __restrict__ Whh,   // [512][128]
    const float* __restrict__ bih, const float* __restrict__ bhh,
    const unsigned short* __restrict__ xemb,  // [S][256][64] bf16 (+64 zero pad)
    int T,
    const float* __restrict__ h0, const float* __restrict__ c0, // null => ones/zeros
    float* __restrict__ hT_out,               // [256][128] fp32 or null
    unsigned short* __restrict__ hs_out)      // [T][256][128] bf16 or null
{
  __shared__ unsigned short hbuf[2][16*136];  // +8 pad/row
  const int tid = threadIdx.x;
  const int wave = tid >> 6, lane = tid & 63;
  const int q = lane >> 4, c16 = lane & 15;
  const int bt0 = blockIdx.x * 4;
  const int hu = wave * 16 + c16;

  // Persistent B frags: kb 0..3 = Whh (K=0..128), kb 4..5 = Wih (K=128..192)
  short8 Bf[4][6];
  float bias[4];
  #pragma unroll
  for (int g = 0; g < 4; ++g){
    const int gcol = g*128 + hu;
    bias[g] = bih[gcol] + bhh[gcol];
    #pragma unroll
    for (int kb = 0; kb < 6; ++kb){
      union { short8 v; unsigned short u[8]; } tmp;
      #pragma unroll
      for (int j = 0; j < 8; ++j){
        int k = kb*32 + q*8 + j;
        float wv = (kb < 4) ? Whh[gcol*H_ + k] : Wih[gcol*E_ + (k - H_)];
        tmp.u[j] = f2bf(wv);
      }
      Bf[g][kb] = tmp.v;
    }
  }

  // LDS: zero both buffers, then fill storage rows {0,4,8,12} of buf0 with h0.
  unsigned short* hflat = &hbuf[0][0];
  for (int idx = tid; idx < 2*16*136; idx += 512) hflat[idx] = 0;
  __syncthreads();
  {
    int b = tid >> 7, k = tid & 127;   // tid < 512 = 4*128
    hbuf[0][(4*b)*136 + k] = h0 ? f2bf(h0[((size_t)(bt0 + b))*H_ + k])
                                : (unsigned short)0x3F80; // bf16(1.0)
  }
  float cst = c0 ? c0[((size_t)(bt0 + q))*H_ + hu] : 0.0f;
  __syncthreads();

  // x window loads: ALL 64 lanes real. Lane A-row = c16 = 4*b_local + dt.
  const int xb = c16 >> 2, xdt = c16 & 3;
  const unsigned short* xbase = xemb + ((size_t)(bt0 + xb))*E_ + q*8;
  const size_t xrow = (size_t)B_*E_;
  auto xwin = [&](int wt)->const unsigned short*{
    int tt = wt + xdt; if (tt > T-1) tt = T-1;   // clamp: garbage rows unused
    return xbase + (size_t)tt * xrow;
  };

  // Prologue: gxA = gx(0..3); nx = x(4..7) in flight.
  float4v gxA[4], gxB[4];
  short8 nx0, nx1;
  { const unsigned short* p = xwin(0);
    nx0 = *(const short8*)p; nx1 = *(const short8*)(p + 32); }
  #pragma unroll
  for (int g = 0; g < 4; ++g){
    float4v t = (float4v){bias[g], bias[g], bias[g], bias[g]};
    t = __builtin_amdgcn_mfma_f32_16x16x32_bf16(nx0, Bf[g][4], t, 0, 0, 0);
    gxA[g] = __builtin_amdgcn_mfma_f32_16x16x32_bf16(nx1, Bf[g][5], t, 0, 0, 0);
  }
  { const unsigned short* p = xwin(4);
    nx0 = *(const short8*)p; nx1 = *(const short8*)(p + 32); }

  short8 Af0 = 0, Af1 = 0, Af2 = 0, Af3 = 0;   // zeros until a lane's first load

  // h A-frag read base: batch (c16>>2) stored at LDS row 4*(c16>>2) = c16&~3.
  // Same address for every dt — only the loading-lane predicate rotates.
  const unsigned short* haR0 = hflat + (c16 & ~3)*136 + q*8;  // buf0
  const unsigned short* haR1 = haR0 + 2176;                   // buf1
  unsigned short* hw0 = hflat + (4*q)*136 + hu;               // write buf0
  unsigned short* hw1 = hw0 + 2176;                           // write buf1
  unsigned short* hsp = hs_out ? (hs_out + ((size_t)(bt0 + q))*H_ + hu) : nullptr;
  float zero_f = 0.0f;
  const float4v z4 = (float4v){0.0f, 0.0f, 0.0f, 0.0f};

  // DT compile-time (integral_constant) -> acc subscripts fold (rule #20).
  // pre(): independent work in the ds_read latency window (BEFORE MFMAs).
  // post(): runs AFTER the main cluster consumed its C-in (gx rotation).
  auto step = [&](int t, auto dtc, float4v (&gxP)[4], auto&& pre, auto&& post){
    constexpr int dt = decltype(dtc)::value;
    const unsigned short* ha = (t & 1) ? haR1 : haR0;
    if ((c16 & 3) == dt){            // this step's h-supplier lanes
      Af0 = *(const short8*)(ha);
      Af1 = *(const short8*)(ha + 32);
      Af2 = *(const short8*)(ha + 64);
      Af3 = *(const short8*)(ha + 96);
    }
    pre();

    // K-split chains: aA = gx + kb0 + kb1 ; aB = kb2 + kb3 (from zero).
    // Fresh h rows {dt,4+dt,8+dt,12+dt} -> product in reg dt; stale rows
    // (other lanes' old Af) only touch regs we never read.
    float4v aA[4], aB[4];
    #pragma unroll
    for (int g = 0; g < 4; ++g)
      aA[g] = __builtin_amdgcn_mfma_f32_16x16x32_bf16(Af0, Bf[g][0], gxP[g], 0, 0, 0);
    #pragma unroll
    for (int g = 0; g < 4; ++g)
      aB[g] = __builtin_amdgcn_mfma_f32_16x16x32_bf16(Af2, Bf[g][2], z4, 0, 0, 0);
    #pragma unroll
    for (int g = 0; g < 4; ++g)
      aA[g] = __builtin_amdgcn_mfma_f32_16x16x32_bf16(Af1, Bf[g][1], aA[g], 0, 0, 0);
    #pragma unroll
    for (int g = 0; g < 4; ++g)
      aB[g] = __builtin_amdgcn_mfma_f32_16x16x32_bf16(Af3, Bf[g][3], aB[g], 0, 0, 0);

    post();   // safe: C-in (gxP) already consumed by the aA cluster above

    float gi = aA[0][dt] + aB[0][dt];
    float gf = aA[1][dt] + aB[1][dt];
    float gg = aA[2][dt] + aB[2][dt];
    float go = aA[3][dt] + aB[3][dt];
    // epilogue: 1 cell/lane (batch q, hidden hu). Shared-rcp pairs:
    // sig(i)*tanh(g) = e^i(e^2g-1) / [(1+e^i)(1+e^2g)], same for o/c.
    float ei  = fexp2(gi * LOG2E);
    float e2g = fexp2(gg * LOG2E2);
    float t1  = (ei * (e2g - 1.0f)) * frcp((1.0f + ei) * (1.0f + e2g));
    float sf  = fsig(gf);
    float c   = fmaf(sf, cst, t1);
    cst = c;
    float eo  = fexp2(go * LOG2E);
    float e2c = fexp2(fminf(c * LOG2E2, 126.0f));   // clamp: c can accumulate
    float h   = (eo * (e2c - 1.0f)) * frcp((1.0f + eo) * (1.0f + e2c));
    unsigned vv;
    asm("v_cvt_pk_bf16_f32 %0, %1, %2" : "=v"(vv) : "v"(h), "v"(zero_f));
    unsigned short hb16 = (unsigned short)vv;
    unsigned short* hw = (t & 1) ? hw0 : hw1;       // write buf (1-cur)
    hw[0] = hb16;
    if (hs_out){ *hsp = hb16; hsp += (size_t)B_*H_; }
    if (hT_out && t == T-1) hT_out[((size_t)(bt0 + q))*H_ + hu] = h;
    // Raw barrier: drain LDS only; globals stay in flight (R7).
    __builtin_amdgcn_sched_barrier(0);
    asm volatile("s_waitcnt lgkmcnt(0)" ::: "memory");
    __builtin_amdgcn_s_barrier();
    __builtin_amdgcn_sched_barrier(0);
  };

  using I0 = std::integral_constant<int,0>;
  using I1 = std::integral_constant<int,1>;
  using I2 = std::integral_constant<int,2>;
  using I3 = std::integral_constant<int,3>;
  auto nop = []{};

  const int nwin = T >> 2, ntail = T & 3;
  for (int w = 0; w < nwin; ++w){
    const int t0 = w << 2;
    step(t0+0, I0{}, gxA, [&]{
      // gxB = gx(t0+4 .. t0+7); consumes nx loaded 3 steps ago.
      #pragma unroll
      for (int g = 0; g < 4; ++g){
        float4v tt = (float4v){bias[g], bias[g], bias[g], bias[g]};
        tt = __builtin_amdgcn_mfma_f32_16x16x32_bf16(nx0, Bf[g][4], tt, 0, 0, 0);
        gxB[g] = __builtin_amdgcn_mfma_f32_16x16x32_bf16(nx1, Bf[g][5], tt, 0, 0, 0);
      }
    }, nop);
    step(t0+1, I1{}, gxA, [&]{
      // issue loads for window w+2; consumed 3 steps later (dt=0 of w+1).
      const unsigned short* p = xwin(t0 + 8);
      nx0 = *(const short8*)p; nx1 = *(const short8*)(p + 32);
    }, nop);
    step(t0+2, I2{}, gxA, nop, nop);
    step(t0+3, I3{}, gxA, nop, [&]{
      // window rotation AFTER the cluster consumed gxA as C-in
      #pragma unroll
      for (int g = 0; g < 4; ++g) gxA[g] = gxB[g];
    });
  }
  // Tail (decoder T=1023: 3 steps). gxA already holds gx(nwin*4 ..).
  if (ntail > 0) step(nwin*4+0, I0{}, gxA, nop, nop);
  if (ntail > 1) step(nwin*4+1, I1{}, gxA, nop, nop);
  if (ntail > 2) step(nwin*4+2, I2{}, gxA, nop, nop);
}

// ---------------- Kernel C: mu/logvar/latent/dh0/dc0 ------------------------
__global__ __launch_bounds__(128) void latent_kernel(
    const float* __restrict__ hT, const float* __restrict__ eps,
    const float* __restrict__ mu_W, const float* __restrict__ mu_b,
    const float* __restrict__ mu_g, const float* __restrict__ mu_be,
    const float* __restrict__ lv_W, const float* __restrict__ lv_b,
    const float* __restrict__ lv_g, const float* __restrict__ lv_be,
    const float* __restrict__ lh_W, const float* __restrict__ lh_b,
    const float* __restrict__ lh_g, const float* __restrict__ lh_be,
    const float* __restrict__ lc_W, const float* __restrict__ lc_b,
    const float* __restrict__ lc_g, const float* __restrict__ lc_be,
    float* __restrict__ out, float* __restrict__ dh0, float* __restrict__ dc0)
{
  const int b = blockIdx.x, tid = threadIdx.x;
  const int wave = tid >> 6, lane = tid & 63;
  __shared__ float shT[H_];
  __shared__ float smu[L_], slv[L_], slat[L_];
  __shared__ float part[2];
  shT[tid] = hT[(size_t)b*H_ + tid];
  __syncthreads();
  {
    const float* W = wave ? lv_W : mu_W;
    float a = (wave ? lv_b : mu_b)[lane];
    for (int k = 0; k < H_; ++k) a += shT[k] * W[lane*H_ + k];
    a = leaky(a);
    float m = wredsum(a) * (1.0f/L_);
    float d = a - m;
    float v = wredsum(d*d) * (1.0f/L_);
    float y = d * rsqrtf(v + 1e-5f) * (wave ? lv_g : mu_g)[lane] + (wave ? lv_be : mu_be)[lane];
    out[(wave ? LV_OFF : MU_OFF) + (size_t)b*L_ + lane] = y;
    if (wave) slv[lane] = y; else smu[lane] = y;
  }
  __syncthreads();
  if (tid < L_) slat[tid] = smu[tid] + eps[(size_t)b*L_ + tid] * expf(0.5f*slv[tid]);
  __syncthreads();
  #pragma unroll 1
  for (int which = 0; which < 2; ++which){
    const float* W = which ? lc_W : lh_W;
    float p = (which ? lc_b : lh_b)[tid];
    for (int k = 0; k < L_; ++k) p += slat[k] * W[tid*L_ + k];
    p = leaky(p);
    float s = wredsum(p);
    if (lane == 0) part[wave] = s;
    __syncthreads();
    float mean = (part[0] + part[1]) * (1.0f/H_);
    __syncthreads();
    float d = p - mean;
    float s2 = wredsum(d*d);
    if (lane == 0) part[wave] = s2;
    __syncthreads();
    float var = (part[0] + part[1]) * (1.0f/H_);
    __syncthreads();
    float y = d * rsqrtf(var + 1e-5f) * (which ? lc_g : lh_g)[tid] + (which ? lc_be : lh_be)[tid];
    (which ? dc0 : dh0)[(size_t)b*H_ + tid] = y;
  }
}

// ---------------- Kernel D: acts/ts heads via MFMA (N=32: 31 acts + ts) -----
__global__ __launch_bounds__(256) void out_kernel(
    const unsigned short* __restrict__ hs,   // [1023][256][128] bf16
    const float* __restrict__ actW, const float* __restrict__ actB,
    const float* __restrict__ timeW, const float* __restrict__ timeB,
    float* __restrict__ out)
{
  const int wave = threadIdx.x >> 6, lane = threadIdx.x & 63;
  const int quad = lane >> 4, c16 = lane & 15;
  const int mt = blockIdx.x * 4 + wave;      // M-tile of 16 rows (r = t*256 + b)
  short8 Wf[2][4]; float biasn[2];
  #pragma unroll
  for (int ti = 0; ti < 2; ++ti){
    const int n = ti*16 + c16;
    biasn[ti] = (n < C_) ? actB[n] : timeB[0];
    #pragma unroll
    for (int kb = 0; kb < 4; ++kb){
      union { short8 v; unsigned short u[8]; } tmp;
      #pragma unroll
      for (int j = 0; j < 8; ++j){
        int k = kb*32 + quad*8 + j;
        tmp.u[j] = f2bf((n < C_) ? actW[n*H_ + k] : timeW[k]);
      }
      Wf[ti][kb] = tmp.v;
    }
  }
  const unsigned short* hp = hs + ((size_t)mt*16 + c16)*H_ + quad*8;
  float4v acc[2];
  #pragma unroll
  for (int ti = 0; ti < 2; ++ti) acc[ti] = (float4v){biasn[ti], biasn[ti], biasn[ti], biasn[ti]};
  #pragma unroll
  for (int kb = 0; kb < 4; ++kb){
    short8 a = *(const short8*)(hp + kb*32);
    acc[0] = __builtin_amdgcn_mfma_f32_16x16x32_bf16(a, Wf[0][kb], acc[0], 0, 0, 0);
    acc[1] = __builtin_amdgcn_mfma_f32_16x16x32_bf16(a, Wf[1][kb], acc[1], 0, 0, 0);
  }
  #pragma unroll
  for (int ti = 0; ti < 2; ++ti){
    const int n = ti*16 + c16;
    #pragma unroll
    for (int r = 0; r < 4; ++r){
      int rr = mt*16 + quad*4 + r;
      int tt = rr >> 8, b = rr & 255;
      float v = acc[ti][r];
      if (n < C_) out[ACTS_OFF + ((size_t)b*1023 + tt)*C_ + n] = v;
      else        out[TS_OFF + (size_t)b*1023 + tt] = v;
    }
  }
}

// ---------------- launch ----------------------------------------------------
extern "C" void kernel_launch(void* const* d_in, const int* in_sizes, int n_in,
                              void* d_out, int out_size, void* d_ws, size_t ws_size,
                              hipStream_t stream)
{
  (void)in_sizes; (void)n_in; (void)out_size; (void)ws_size;
  const float* x       = (const float*)d_in[0];
  const float* eps     = (const float*)d_in[1];
  const float* init_W  = (const float*)d_in[2];
  const float* init_b  = (const float*)d_in[3];
  const float* init_g  = (const float*)d_in[4];
  const float* init_be = (const float*)d_in[5];
  const float* enc_Wih = (const float*)d_in[6];
  const float* enc_Whh = (const float*)d_in[7];
  const float* enc_bih = (const float*)d_in[8];
  const float* enc_bhh = (const float*)d_in[9];
  const float* mu_W  = (const float*)d_in[10];
  const float* mu_b  = (const float*)d_in[11];
  const float* mu_g  = (const float*)d_in[12];
  const float* mu_be = (const float*)d_in[13];
  const float* lv_W  = (const float*)d_in[14];
  const float* lv_b  = (const float*)d_in[15];
  const float* lv_g  = (const float*)d_in[16];
  const float* lv_be = (const float*)d_in[17];
  const float* dec_Wih = (const float*)d_in[18];
  const float* dec_Whh = (const float*)d_in[19];
  const float* dec_bih = (const float*)d_in[20];
  const float* dec_bhh = (const float*)d_in[21];
  const float* lh_W  = (const float*)d_in[22];
  const float* lh_b  = (const float*)d_in[23];
  const float* lh_g  = (const float*)d_in[24];
  const float* lh_be = (const float*)d_in[25];
  const float* lc_W  = (const float*)d_in[26];
  const float* lc_b  = (const float*)d_in[27];
  const float* lc_g  = (const float*)d_in[28];
  const float* lc_be = (const float*)d_in[29];
  const float* act_W  = (const float*)d_in[30];
  const float* act_b  = (const float*)d_in[31];
  const float* time_W = (const float*)d_in[32];
  const float* time_b = (const float*)d_in[33];
  float* out = (float*)d_out;

  // workspace: xemb [1024][256][64] bf16 + 64-short zero pad, hs, hT, dh0, dc0
  unsigned short* xemb = (unsigned short*)d_ws;
  unsigned short* hs   = xemb + (size_t)S_*B_*E_ + 64;       // after pad
  float* hT  = (float*)(hs + (size_t)(S_-1)*B_*H_);
  float* dh0 = hT  + B_*H_;
  float* dc0 = dh0 + B_*H_;

  init_kernel<<<dim3((B_*S_)/4), dim3(256), 0, stream>>>(
      x, init_W, init_b, init_g, init_be, xemb);

  lstm_kernel<<<dim3(64), dim3(512), 0, stream>>>(
      enc_Wih, enc_Whh, enc_bih, enc_bhh, xemb, S_,
      nullptr, nullptr, hT, nullptr);

  latent_kernel<<<dim3(B_), dim3(128), 0, stream>>>(
      hT, eps, mu_W, mu_b, mu_g, mu_be, lv_W, lv_b, lv_g, lv_be,
      lh_W, lh_b, lh_g, lh_be, lc_W, lc_b, lc_g, lc_be, out, dh0, dc0);

  lstm_kernel<<<dim3(64), dim3(512), 0, stream>>>(
      dec_Wih, dec_Whh, dec_bih, dec_bhh, xemb, S_-1,
      dh0, dc0, nullptr, hs);

  out_kernel<<<dim3((B_*(S_-1))/16/4), dim3(256), 0, stream>>>(
      hs, act_W, act_b, time_W, time_b, out);
}

// Round 7
// 1173.618 us; speedup vs baseline: 1.3567x; 1.1537x over previous
//
#include <hip/hip_runtime.h>
#include <hip/hip_bf16.h>
#include <type_traits>

// LogVAE. R13 (from R12 @1354us, lstm 2x491):
//  lstm UNCHANGED (R12 structure: lane-rotated reg-dt, gx C-in, K-split,
//  pre/post hooks, lgkmcnt-only barrier).
//  init_kernel rewritten (est ~85-150us of the 372us non-lstm time):
//   - x row is wave-uniform -> readfirstlane + SGPR s_loads (kills 32
//     __shfl broadcasts per row)
//   - W row cached in VGPRs once per wave (8x float4), reused for 16 rows
//   - grid 65536 -> 4096 blocks, 16 rows/wave

#define B_ 256
#define S_ 1024
#define NF_ 32
#define E_ 64
#define H_ 128
#define L_ 64
#define C_ 31

#define ACTS_OFF 0
#define TS_OFF   8118528   // 256*1023*31
#define MU_OFF   8380416   // + 256*1023
#define LV_OFF   8396800   // + 256*64

#define LOG2E  1.44269504f
#define LOG2E2 2.88539008f

typedef __attribute__((ext_vector_type(8))) short short8;
typedef __attribute__((ext_vector_type(4))) float float4v;

__device__ inline unsigned short f2bf(float x){
  union { float f; unsigned u; } a; a.f = x;
  unsigned r = a.u + 0x7FFFu + ((a.u >> 16) & 1u);
  return (unsigned short)(r >> 16);
}
__device__ inline float frcp(float x){
#if __has_builtin(__builtin_amdgcn_rcpf)
  return __builtin_amdgcn_rcpf(x);
#else
  return 1.0f / x;
#endif
}
__device__ inline float fexp2(float x){
#if __has_builtin(__builtin_amdgcn_exp2f)
  return __builtin_amdgcn_exp2f(x);
#else
  return exp2f(x);
#endif
}
__device__ inline float fsig(float x){ return frcp(1.0f + fexp2(-LOG2E*x)); }
__device__ inline float leaky(float x){ return x >= 0.0f ? x : 0.01f*x; }
__device__ inline float wredsum(float v){
  v += __shfl_xor(v, 32, 64);
  v += __shfl_xor(v, 16, 64);
  v += __shfl_xor(v,  8, 64);
  v += __shfl_xor(v,  4, 64);
  v += __shfl_xor(v,  2, 64);
  v += __shfl_xor(v,  1, 64);
  return v;
}

// ---------------- Kernel A: x_emb = LN(leaky(x @ W.T + b)) -> bf16 [S][B][E] --
// 4 waves/block, 16 rows/wave. Per wave: W row (lane's output) cached in
// VGPRs once; per row: x loaded via SGPRs (wave-uniform), 32 v_fmac(s,v).
#define INIT_ROWS 16
__global__ __launch_bounds__(256) void init_kernel(
    const float* __restrict__ x, const float* __restrict__ W,
    const float* __restrict__ bias, const float* __restrict__ gam,
    const float* __restrict__ beta, unsigned short* __restrict__ xemb)
{
  if (blockIdx.x == 0 && threadIdx.x < 64)
    xemb[(size_t)S_*B_*E_ + threadIdx.x] = 0;

  const int wave = threadIdx.x >> 6, lane = threadIdx.x & 63;
  // per-lane W row + LN consts (persist across the 16 rows)
  float wf[NF_];
  {
    const float4* wr = (const float4*)(W + lane * NF_);
    #pragma unroll
    for (int j = 0; j < NF_/4; ++j){
      float4 t = wr[j];
      wf[4*j+0] = t.x; wf[4*j+1] = t.y; wf[4*j+2] = t.z; wf[4*j+3] = t.w;
    }
  }
  const float bb = bias[lane], gg = gam[lane], be = beta[lane];

  const int r0 = (blockIdx.x * 4 + wave) * INIT_ROWS;
  for (int rr = 0; rr < INIT_ROWS; ++rr){
    const int ru = __builtin_amdgcn_readfirstlane(r0 + rr);  // wave-uniform row
    const int b = ru >> 10, s = ru & 1023;
    const float* xr = x + (size_t)ru * NF_;   // SGPR-based -> s_loads
    float acc = bb;
    #pragma unroll
    for (int k = 0; k < NF_; ++k)
      acc = fmaf(xr[k], wf[k], acc);
    acc = leaky(acc);
    float m = wredsum(acc) * (1.0f/64.0f);
    float d = acc - m;
    float v = wredsum(d*d) * (1.0f/64.0f);
    float y = d * rsqrtf(v + 1e-5f) * gg + be;
    xemb[((size_t)s * B_ + b) * E_ + lane] = f2bf(y);   // [S][B][E]
  }
}

// ---------------- Kernel B: LSTM recurrence (UNCHANGED from R12) -------------
// grid=64 (4 batch/WG), block=512 (8 waves). Wave w owns i,f,g,o gates of
// hidden [16w,16w+16). At step dt (t mod 4), h A-rows = {dt,4+dt,8+dt,12+dt}
// (batch b at row 4b+dt, supplied by lanes c16&3==dt) -> h-product lands at
// reg dt = same slot as time-batched gx (A rows 4b+dt) and the gate read.
__global__ __launch_bounds__(512, 2) void lstm_kernel(
    const float* __restrict__ Wih,   // [512][64]
    const float* __restrict__ Whh,   // [512][128]
    const float* __restrict__ bih, const float* __restrict__ bhh,
    const unsigned short* __restrict__ xemb,  // [S][256][64] bf16 (+64 zero pad)
    int T,
    const float* __restrict__ h0, const float* __restrict__ c0, // null => ones/zeros
    float* __restrict__ hT_out,               // [256][128] fp32 or null
    unsigned short* __restrict__ hs_out)      // [T][256][128] bf16 or null
{
  __shared__ unsigned short hbuf[2][16*136];  // +8 pad/row
  const int tid = threadIdx.x;
  const int wave = tid >> 6, lane = tid & 63;
  const int q = lane >> 4, c16 = lane & 15;
  const int bt0 = blockIdx.x * 4;
  const int hu = wave * 16 + c16;

  // Persistent B frags: kb 0..3 = Whh (K=0..128), kb 4..5 = Wih (K=128..192)
  short8 Bf[4][6];
  float bias[4];
  #pragma unroll
  for (int g = 0; g < 4; ++g){
    const int gcol = g*128 + hu;
    bias[g] = bih[gcol] + bhh[gcol];
    #pragma unroll
    for (int kb = 0; kb < 6; ++kb){
      union { short8 v; unsigned short u[8]; } tmp;
      #pragma unroll
      for (int j = 0; j < 8; ++j){
        int k = kb*32 + q*8 + j;
        float wv = (kb < 4) ? Whh[gcol*H_ + k] : Wih[gcol*E_ + (k - H_)];
        tmp.u[j] = f2bf(wv);
      }
      Bf[g][kb] = tmp.v;
    }
  }

  // LDS: zero both buffers, then fill storage rows {0,4,8,12} of buf0 with h0.
  unsigned short* hflat = &hbuf[0][0];
  for (int idx = tid; idx < 2*16*136; idx += 512) hflat[idx] = 0;
  __syncthreads();
  {
    int b = tid >> 7, k = tid & 127;   // tid < 512 = 4*128
    hbuf[0][(4*b)*136 + k] = h0 ? f2bf(h0[((size_t)(bt0 + b))*H_ + k])
                                : (unsigned short)0x3F80; // bf16(1.0)
  }
  float cst = c0 ? c0[((size_t)(bt0 + q))*H_ + hu] : 0.0f;
  __syncthreads();

  // x window loads: ALL 64 lanes real. Lane A-row = c16 = 4*b_local + dt.
  const int xb = c16 >> 2, xdt = c16 & 3;
  const unsigned short* xbase = xemb + ((size_t)(bt0 + xb))*E_ + q*8;
  const size_t xrow = (size_t)B_*E_;
  auto xwin = [&](int wt)->const unsigned short*{
    int tt = wt + xdt; if (tt > T-1) tt = T-1;   // clamp: garbage rows unused
    return xbase + (size_t)tt * xrow;
  };

  // Prologue: gxA = gx(0..3); nx = x(4..7) in flight.
  float4v gxA[4], gxB[4];
  short8 nx0, nx1;
  { const unsigned short* p = xwin(0);
    nx0 = *(const short8*)p; nx1 = *(const short8*)(p + 32); }
  #pragma unroll
  for (int g = 0; g < 4; ++g){
    float4v t = (float4v){bias[g], bias[g], bias[g], bias[g]};
    t = __builtin_amdgcn_mfma_f32_16x16x32_bf16(nx0, Bf[g][4], t, 0, 0, 0);
    gxA[g] = __builtin_amdgcn_mfma_f32_16x16x32_bf16(nx1, Bf[g][5], t, 0, 0, 0);
  }
  { const unsigned short* p = xwin(4);
    nx0 = *(const short8*)p; nx1 = *(const short8*)(p + 32); }

  short8 Af0 = 0, Af1 = 0, Af2 = 0, Af3 = 0;   // zeros until a lane's first load

  // h A-frag read base: batch (c16>>2) stored at LDS row 4*(c16>>2) = c16&~3.
  // Same address for every dt — only the loading-lane predicate rotates.
  const unsigned short* haR0 = hflat + (c16 & ~3)*136 + q*8;  // buf0
  const unsigned short* haR1 = haR0 + 2176;                   // buf1
  unsigned short* hw0 = hflat + (4*q)*136 + hu;               // write buf0
  unsigned short* hw1 = hw0 + 2176;                           // write buf1
  unsigned short* hsp = hs_out ? (hs_out + ((size_t)(bt0 + q))*H_ + hu) : nullptr;
  float zero_f = 0.0f;
  const float4v z4 = (float4v){0.0f, 0.0f, 0.0f, 0.0f};

  // DT compile-time (integral_constant) -> acc subscripts fold (rule #20).
  // pre(): independent work in the ds_read latency window (BEFORE MFMAs).
  // post(): runs AFTER the main cluster consumed its C-in (gx rotation).
  auto step = [&](int t, auto dtc, float4v (&gxP)[4], auto&& pre, auto&& post){
    constexpr int dt = decltype(dtc)::value;
    const unsigned short* ha = (t & 1) ? haR1 : haR0;
    if ((c16 & 3) == dt){            // this step's h-supplier lanes
      Af0 = *(const short8*)(ha);
      Af1 = *(const short8*)(ha + 32);
      Af2 = *(const short8*)(ha + 64);
      Af3 = *(const short8*)(ha + 96);
    }
    pre();

    // K-split chains: aA = gx + kb0 + kb1 ; aB = kb2 + kb3 (from zero).
    // Fresh h rows {dt,4+dt,8+dt,12+dt} -> product in reg dt; stale rows
    // (other lanes' old Af) only touch regs we never read.
    float4v aA[4], aB[4];
    #pragma unroll
    for (int g = 0; g < 4; ++g)
      aA[g] = __builtin_amdgcn_mfma_f32_16x16x32_bf16(Af0, Bf[g][0], gxP[g], 0, 0, 0);
    #pragma unroll
    for (int g = 0; g < 4; ++g)
      aB[g] = __builtin_amdgcn_mfma_f32_16x16x32_bf16(Af2, Bf[g][2], z4, 0, 0, 0);
    #pragma unroll
    for (int g = 0; g < 4; ++g)
      aA[g] = __builtin_amdgcn_mfma_f32_16x16x32_bf16(Af1, Bf[g][1], aA[g], 0, 0, 0);
    #pragma unroll
    for (int g = 0; g < 4; ++g)
      aB[g] = __builtin_amdgcn_mfma_f32_16x16x32_bf16(Af3, Bf[g][3], aB[g], 0, 0, 0);

    post();   // safe: C-in (gxP) already consumed by the aA cluster above

    float gi = aA[0][dt] + aB[0][dt];
    float gf = aA[1][dt] + aB[1][dt];
    float gg = aA[2][dt] + aB[2][dt];
    float go = aA[3][dt] + aB[3][dt];
    // epilogue: 1 cell/lane (batch q, hidden hu). Shared-rcp pairs:
    // sig(i)*tanh(g) = e^i(e^2g-1) / [(1+e^i)(1+e^2g)], same for o/c.
    float ei  = fexp2(gi * LOG2E);
    float e2g = fexp2(gg * LOG2E2);
    float t1  = (ei * (e2g - 1.0f)) * frcp((1.0f + ei) * (1.0f + e2g));
    float sf  = fsig(gf);
    float c   = fmaf(sf, cst, t1);
    cst = c;
    float eo  = fexp2(go * LOG2E);
    float e2c = fexp2(fminf(c * LOG2E2, 126.0f));   // clamp: c can accumulate
    float h   = (eo * (e2c - 1.0f)) * frcp((1.0f + eo) * (1.0f + e2c));
    unsigned vv;
    asm("v_cvt_pk_bf16_f32 %0, %1, %2" : "=v"(vv) : "v"(h), "v"(zero_f));
    unsigned short hb16 = (unsigned short)vv;
    unsigned short* hw = (t & 1) ? hw0 : hw1;       // write buf (1-cur)
    hw[0] = hb16;
    if (hs_out){ *hsp = hb16; hsp += (size_t)B_*H_; }
    if (hT_out && t == T-1) hT_out[((size_t)(bt0 + q))*H_ + hu] = h;
    // Raw barrier: drain LDS only; globals stay in flight (R7).
    __builtin_amdgcn_sched_barrier(0);
    asm volatile("s_waitcnt lgkmcnt(0)" ::: "memory");
    __builtin_amdgcn_s_barrier();
    __builtin_amdgcn_sched_barrier(0);
  };

  using I0 = std::integral_constant<int,0>;
  using I1 = std::integral_constant<int,1>;
  using I2 = std::integral_constant<int,2>;
  using I3 = std::integral_constant<int,3>;
  auto nop = []{};

  const int nwin = T >> 2, ntail = T & 3;
  for (int w = 0; w < nwin; ++w){
    const int t0 = w << 2;
    step(t0+0, I0{}, gxA, [&]{
      // gxB = gx(t0+4 .. t0+7); consumes nx loaded 3 steps ago.
      #pragma unroll
      for (int g = 0; g < 4; ++g){
        float4v tt = (float4v){bias[g], bias[g], bias[g], bias[g]};
        tt = __builtin_amdgcn_mfma_f32_16x16x32_bf16(nx0, Bf[g][4], tt, 0, 0, 0);
        gxB[g] = __builtin_amdgcn_mfma_f32_16x16x32_bf16(nx1, Bf[g][5], tt, 0, 0, 0);
      }
    }, nop);
    step(t0+1, I1{}, gxA, [&]{
      // issue loads for window w+2; consumed 3 steps later (dt=0 of w+1).
      const unsigned short* p = xwin(t0 + 8);
      nx0 = *(const short8*)p; nx1 = *(const short8*)(p + 32);
    }, nop);
    step(t0+2, I2{}, gxA, nop, nop);
    step(t0+3, I3{}, gxA, nop, [&]{
      // window rotation AFTER the cluster consumed gxA as C-in
      #pragma unroll
      for (int g = 0; g < 4; ++g) gxA[g] = gxB[g];
    });
  }
  // Tail (decoder T=1023: 3 steps). gxA already holds gx(nwin*4 ..).
  if (ntail > 0) step(nwin*4+0, I0{}, gxA, nop, nop);
  if (ntail > 1) step(nwin*4+1, I1{}, gxA, nop, nop);
  if (ntail > 2) step(nwin*4+2, I2{}, gxA, nop, nop);
}

// ---------------- Kernel C: mu/logvar/latent/dh0/dc0 ------------------------
__global__ __launch_bounds__(128) void latent_kernel(
    const float* __restrict__ hT, const float* __restrict__ eps,
    const float* __restrict__ mu_W, const float* __restrict__ mu_b,
    const float* __restrict__ mu_g, const float* __restrict__ mu_be,
    const float* __restrict__ lv_W, const float* __restrict__ lv_b,
    const float* __restrict__ lv_g, const float* __restrict__ lv_be,
    const float* __restrict__ lh_W, const float* __restrict__ lh_b,
    const float* __restrict__ lh_g, const float* __restrict__ lh_be,
    const float* __restrict__ lc_W, const float* __restrict__ lc_b,
    const float* __restrict__ lc_g, const float* __restrict__ lc_be,
    float* __restrict__ out, float* __restrict__ dh0, float* __restrict__ dc0)
{
  const int b = blockIdx.x, tid = threadIdx.x;
  const int wave = tid >> 6, lane = tid & 63;
  __shared__ float shT[H_];
  __shared__ float smu[L_], slv[L_], slat[L_];
  __shared__ float part[2];
  shT[tid] = hT[(size_t)b*H_ + tid];
  __syncthreads();
  {
    const float* W = wave ? lv_W : mu_W;
    float a = (wave ? lv_b : mu_b)[lane];
    for (int k = 0; k < H_; ++k) a += shT[k] * W[lane*H_ + k];
    a = leaky(a);
    float m = wredsum(a) * (1.0f/L_);
    float d = a - m;
    float v = wredsum(d*d) * (1.0f/L_);
    float y = d * rsqrtf(v + 1e-5f) * (wave ? lv_g : mu_g)[lane] + (wave ? lv_be : mu_be)[lane];
    out[(wave ? LV_OFF : MU_OFF) + (size_t)b*L_ + lane] = y;
    if (wave) slv[lane] = y; else smu[lane] = y;
  }
  __syncthreads();
  if (tid < L_) slat[tid] = smu[tid] + eps[(size_t)b*L_ + tid] * expf(0.5f*slv[tid]);
  __syncthreads();
  #pragma unroll 1
  for (int which = 0; which < 2; ++which){
    const float* W = which ? lc_W : lh_W;
    float p = (which ? lc_b : lh_b)[tid];
    for (int k = 0; k < L_; ++k) p += slat[k] * W[tid*L_ + k];
    p = leaky(p);
    float s = wredsum(p);
    if (lane == 0) part[wave] = s;
    __syncthreads();
    float mean = (part[0] + part[1]) * (1.0f/H_);
    __syncthreads();
    float d = p - mean;
    float s2 = wredsum(d*d);
    if (lane == 0) part[wave] = s2;
    __syncthreads();
    float var = (part[0] + part[1]) * (1.0f/H_);
    __syncthreads();
    float y = d * rsqrtf(var + 1e-5f) * (which ? lc_g : lh_g)[tid] + (which ? lc_be : lh_be)[tid];
    (which ? dc0 : dh0)[(size_t)b*H_ + tid] = y;
  }
}

// ---------------- Kernel D: acts/ts heads via MFMA (N=32: 31 acts + ts) -----
__global__ __launch_bounds__(256) void out_kernel(
    const unsigned short* __restrict__ hs,   // [1023][256][128] bf16
    const float* __restrict__ actW, const float* __restrict__ actB,
    const float* __restrict__ timeW, const float* __restrict__ timeB,
    float* __restrict__ out)
{
  const int wave = threadIdx.x >> 6, lane = threadIdx.x & 63;
  const int quad = lane >> 4, c16 = lane & 15;
  const int mt = blockIdx.x * 4 + wave;      // M-tile of 16 rows (r = t*256 + b)
  short8 Wf[2][4]; float biasn[2];
  #pragma unroll
  for (int ti = 0; ti < 2; ++ti){
    const int n = ti*16 + c16;
    biasn[ti] = (n < C_) ? actB[n] : timeB[0];
    #pragma unroll
    for (int kb = 0; kb < 4; ++kb){
      union { short8 v; unsigned short u[8]; } tmp;
      #pragma unroll
      for (int j = 0; j < 8; ++j){
        int k = kb*32 + quad*8 + j;
        tmp.u[j] = f2bf((n < C_) ? actW[n*H_ + k] : timeW[k]);
      }
      Wf[ti][kb] = tmp.v;
    }
  }
  const unsigned short* hp = hs + ((size_t)mt*16 + c16)*H_ + quad*8;
  float4v acc[2];
  #pragma unroll
  for (int ti = 0; ti < 2; ++ti) acc[ti] = (float4v){biasn[ti], biasn[ti], biasn[ti], biasn[ti]};
  #pragma unroll
  for (int kb = 0; kb < 4; ++kb){
    short8 a = *(const short8*)(hp + kb*32);
    acc[0] = __builtin_amdgcn_mfma_f32_16x16x32_bf16(a, Wf[0][kb], acc[0], 0, 0, 0);
    acc[1] = __builtin_amdgcn_mfma_f32_16x16x32_bf16(a, Wf[1][kb], acc[1], 0, 0, 0);
  }
  #pragma unroll
  for (int ti = 0; ti < 2; ++ti){
    const int n = ti*16 + c16;
    #pragma unroll
    for (int r = 0; r < 4; ++r){
      int rr = mt*16 + quad*4 + r;
      int tt = rr >> 8, b = rr & 255;
      float v = acc[ti][r];
      if (n < C_) out[ACTS_OFF + ((size_t)b*1023 + tt)*C_ + n] = v;
      else        out[TS_OFF + (size_t)b*1023 + tt] = v;
    }
  }
}

// ---------------- launch ----------------------------------------------------
extern "C" void kernel_launch(void* const* d_in, const int* in_sizes, int n_in,
                              void* d_out, int out_size, void* d_ws, size_t ws_size,
                              hipStream_t stream)
{
  (void)in_sizes; (void)n_in; (void)out_size; (void)ws_size;
  const float* x       = (const float*)d_in[0];
  const float* eps     = (const float*)d_in[1];
  const float* init_W  = (const float*)d_in[2];
  const float* init_b  = (const float*)d_in[3];
  const float* init_g  = (const float*)d_in[4];
  const float* init_be = (const float*)d_in[5];
  const float* enc_Wih = (const float*)d_in[6];
  const float* enc_Whh = (const float*)d_in[7];
  const float* enc_bih = (const float*)d_in[8];
  const float* enc_bhh = (const float*)d_in[9];
  const float* mu_W  = (const float*)d_in[10];
  const float* mu_b  = (const float*)d_in[11];
  const float* mu_g  = (const float*)d_in[12];
  const float* mu_be = (const float*)d_in[13];
  const float* lv_W  = (const float*)d_in[14];
  const float* lv_b  = (const float*)d_in[15];
  const float* lv_g  = (const float*)d_in[16];
  const float* lv_be = (const float*)d_in[17];
  const float* dec_Wih = (const float*)d_in[18];
  const float* dec_Whh = (const float*)d_in[19];
  const float* dec_bih = (const float*)d_in[20];
  const float* dec_bhh = (const float*)d_in[21];
  const float* lh_W  = (const float*)d_in[22];
  const float* lh_b  = (const float*)d_in[23];
  const float* lh_g  = (const float*)d_in[24];
  const float* lh_be = (const float*)d_in[25];
  const float* lc_W  = (const float*)d_in[26];
  const float* lc_b  = (const float*)d_in[27];
  const float* lc_g  = (const float*)d_in[28];
  const float* lc_be = (const float*)d_in[29];
  const float* act_W  = (const float*)d_in[30];
  const float* act_b  = (const float*)d_in[31];
  const float* time_W = (const float*)d_in[32];
  const float* time_b = (const float*)d_in[33];
  float* out = (float*)d_out;

  // workspace: xemb [1024][256][64] bf16 + 64-short zero pad, hs, hT, dh0, dc0
  unsigned short* xemb = (unsigned short*)d_ws;
  unsigned short* hs   = xemb + (size_t)S_*B_*E_ + 64;       // after pad
  float* hT  = (float*)(hs + (size_t)(S_-1)*B_*H_);
  float* dh0 = hT  + B_*H_;
  float* dc0 = dh0 + B_*H_;

  init_kernel<<<dim3((B_*S_)/(4*INIT_ROWS)), dim3(256), 0, stream>>>(
      x, init_W, init_b, init_g, init_be, xemb);

  lstm_kernel<<<dim3(64), dim3(512), 0, stream>>>(
      enc_Wih, enc_Whh, enc_bih, enc_bhh, xemb, S_,
      nullptr, nullptr, hT, nullptr);

  latent_kernel<<<dim3(B_), dim3(128), 0, stream>>>(
      hT, eps, mu_W, mu_b, mu_g, mu_be, lv_W, lv_b, lv_g, lv_be,
      lh_W, lh_b, lh_g, lh_be, lc_W, lc_b, lc_g, lc_be, out, dh0, dc0);

  lstm_kernel<<<dim3(64), dim3(512), 0, stream>>>(
      dec_Wih, dec_Whh, dec_bih, dec_bhh, xemb, S_-1,
      dh0, dc0, nullptr, hs);

  out_kernel<<<dim3((B_*(S_-1))/16/4), dim3(256), 0, stream>>>(
      hs, act_W, act_b, time_W, time_b, out);
}